// Round 9
// baseline (169.747 us; speedup 1.0000x reference)
//
#include <hip/hip_runtime.h>
#include <hip/hip_bf16.h>
#include <math.h>

#define LEN 128
#define NCPAD 8320           // 8256 cells + zeroed pad (masked-lane reads stay finite)
#define TOTAL 349504
#define NCONSTR 8
#define BONUS 1000.0f
#define NT 512

__device__ __forceinline__ int OFFi(int n){ return (n*(257-n))>>1; }

// Barrier WITHOUT vmcnt drain (score prefetch stays in flight; T4 discipline).
__device__ __forceinline__ void level_barrier(){
    __builtin_amdgcn_sched_barrier(0);
    asm volatile("s_waitcnt lgkmcnt(0)\n\ts_barrier" ::: "memory");
    __builtin_amdgcn_sched_barrier(0);
}

__device__ __forceinline__ float dpp_xor1_max(float v){
    int r = __builtin_amdgcn_update_dpp(0, __float_as_int(v), 0xB1, 0xF, 0xF, true);
    return fmaxf(v, __int_as_float(r));
}
__device__ __forceinline__ float dpp_xor2_max(float v){
    int r = __builtin_amdgcn_update_dpp(0, __float_as_int(v), 0x4E, 0xF, 0xF, true);
    return fmaxf(v, __int_as_float(r));
}
template<int LG>
__device__ __forceinline__ void redmax2(float& a, float& b){
    #pragma unroll
    for (int mm=(1<<LG)>>1; mm>=4; mm>>=1){
        a=fmaxf(a,__shfl_xor(a,mm));
        b=fmaxf(b,__shfl_xor(b,mm));
    }
    if constexpr (LG>=2){ a=dpp_xor2_max(a); b=dpp_xor2_max(b); }
    if constexpr (LG>=1){ a=dpp_xor1_max(a); b=dpp_xor1_max(b); }
}

__device__ __forceinline__ bool chit(int q, const int4 c0, const int4 c1){
    return (q==c0.x)|(q==c0.y)|(q==c0.z)|(q==c0.w)|
           (q==c1.x)|(q==c1.y)|(q==c1.z)|(q==c1.w);
}

// One phase = level l (and level l+1 if JB>0, fused in-wave).
// Mapping: pos = S*wave + group (stride-S; boundary group G-1 is redundant
// when S==G-1). Level-(l+1) race terms (n==0 right child, n==l left child,
// both row l) come from registers: own cell value + shfl_down(T) neighbor.
// LGn/Sn/JNA/JNB: prefetch next phase's scores (guards identical to consume).
template<int LG,int S,int JA,int JB,int LGn,int Sn,int JNA,int JNB>
__device__ __forceinline__ void phase(const int l, int& soff,
    const float* __restrict__ gsc, float2* __restrict__ chart,
    float (&xa)[16], float (&xb)[16], float (&na)[16], float (&nb)[16],
    const int4 cc0, const int4 cc1, const int tid)
{
    const int N = l, L = LEN - l;
    constexpr int T = 1<<LG, G = 64>>LG;
    constexpr bool FUSED = (JB>0);
    const int w   = tid>>6;
    const int grp = (tid>>LG)&(G-1);
    const int pos = S*w + grp;
    const int sub = tid&(T-1);
    const bool owner = (S==G) || (grp != G-1);
    const bool actA = (pos < L);
    const bool actB = FUSED && owner && (pos+1 < L);

    // ---- burst A: level-l child reads (rows <= l-1, all final) ----
    float2 lva[JA], rva[JA];
    if (actA){
        #pragma unroll
        for(int j=0;j<JA;j++){
            const int n = sub + j*T;
            const bool v = (n < N);
            const int li = OFFi(n)+pos;
            const int ri = v ? (OFFi(N-1-n)+pos+n+1) : 0;
            lva[j]=chart[li]; rva[j]=chart[ri];
        }
    }
    // ---- burst B: level-(l+1) reads; race terms clamped to row0 ----
    float2 lvb[FUSED?JB:1], rvb[FUSED?JB:1];
    if constexpr (FUSED){
        if (actB){
            #pragma unroll
            for(int j=0;j<JB;j++){
                const int n = sub + j*T;
                const bool vb = (n <= N);
                const int li = (n==N) ? 0 : (OFFi(n)+pos);
                const int ri = (n==0) ? 0 : (vb ? (OFFi(N-n)+pos+n+1) : 0);
                lvb[j]=chart[li]; rvb[j]=chart[ri];
            }
        }
    }

    // ---- prefetch next phase's scores (in flight across the barrier) ----
    const int soffB = soff + L*N;
    const int soffN = FUSED ? (soffB + (L-1)*(N+1)) : soffB;
    if constexpr (JNA>0){
        constexpr int Tn=1<<LGn, Gn=64>>LGn;
        const int grpn=(tid>>LGn)&(Gn-1);
        const int posn=Sn*w + grpn;
        const int subn=tid&(Tn-1);
        const int Ln1 = FUSED ? (L-2) : (L-1);
        const int Nn1 = FUSED ? (N+2) : (N+1);
        if (posn < Ln1){
            const float* __restrict__ gp = gsc + soffN + posn*Nn1 + subn;
            #pragma unroll
            for(int j=0;j<JNA;j++) if (subn + j*Tn < Nn1) na[j]=gp[j*Tn];
        }
        if constexpr (JNB>0){
            const int Ln2 = Ln1-1, Nn2 = Nn1+1;
            if (posn < Ln2){
                const float* __restrict__ gp2 = gsc + soffN + Ln1*Nn1 + posn*Nn2 + subn;
                #pragma unroll
                for(int j=0;j<JNB;j++) if (subn + j*Tn < Nn2) nb[j]=gp2[j*Tn];
            }
        }
    }

    // ---- compute level l ----
    float bp=-INFINITY, bc=-INFINITY;
    if (actA){
        #pragma unroll
        for(int j=0;j<JA;j++){
            const int n = sub + j*T;
            const float x = (n<N) ? xa[j] : -INFINITY;
            bp=fmaxf(bp, lva[j].x + rva[j].x + x);
            bc=fmaxf(bc, lva[j].y + rva[j].y + x);
        }
    }
    redmax2<LG>(bp,bc);
    const int q = OFFi(N)+pos;
    const float cvp = bp;
    const float cvc = bc + (chit(q,cc0,cc1)?BONUS:0.f);
    if (actA && sub==0 && owner) chart[q]=make_float2(cvp,cvc);

    // ---- compute level l+1 (register-forwarded row-l terms) ----
    if constexpr (FUSED){
        const float nvp = __shfl_down(cvp, T);
        const float nvc = __shfl_down(cvc, T);
        float b2p=-INFINITY, b2c=-INFINITY;
        if (actB){
            const int jNl = N>>LG;
            const int sNl = N&(T-1);
            #pragma unroll
            for(int j=0;j<JB;j++){
                const int n = sub + j*T;
                float lx=lvb[j].x, ly=lvb[j].y, rx=rvb[j].x, ry=rvb[j].y;
                if (j==0){ const bool r0=(sub==0); rx=r0?nvp:rx; ry=r0?nvc:ry; }
                if (j==jNl){ const bool sl=(sub==sNl); lx=sl?cvp:lx; ly=sl?cvc:ly; }
                const float x = (n<=N) ? xb[j] : -INFINITY;
                b2p=fmaxf(b2p, lx+rx+x);
                b2c=fmaxf(b2c, ly+ry+x);
            }
        }
        redmax2<LG>(b2p,b2c);
        if (actB && sub==0){
            const int q2 = OFFi(N+1)+pos;
            chart[q2]=make_float2(b2p, b2c + (chit(q2,cc0,cc1)?BONUS:0.f));
        }
    }

    level_barrier();
    soff = soffN;
}

// Fused T=4 pairs: levels 4K-4 and 4K-2 (each covering (l,l+1)), JA=JB=K.
template<int K>
__device__ __forceinline__ void segf4(int& soff, const float* __restrict__ g,
    float2* __restrict__ chart,
    float (&X0)[16], float (&X1)[16], float (&Y0)[16], float (&Y1)[16],
    const int4 cc0, const int4 cc1, const int tid)
{
    phase<2,15,K,K, 2,15,K,K>    (4*K-4, soff, g, chart, X0,X1, Y0,Y1, cc0,cc1, tid);
    phase<2,15,K,K, 2,15,K+1,K+1>(4*K-2, soff, g, chart, Y0,Y1, X0,X1, cc0,cc1, tid);
}

// Fused T=8 quads: levels 8K-8,8K-6,8K-4,8K-2.
template<int K>
__device__ __forceinline__ void segf8(int& soff, const float* __restrict__ g,
    float2* __restrict__ chart,
    float (&X0)[16], float (&X1)[16], float (&Y0)[16], float (&Y1)[16],
    const int4 cc0, const int4 cc1, const int tid)
{
    phase<3,7,K-1,K, 3,7,K,K>  (8*K-8, soff, g, chart, X0,X1, Y0,Y1, cc0,cc1, tid);
    phase<3,7,K,K,   3,7,K,K>  (8*K-6, soff, g, chart, Y0,Y1, X0,X1, cc0,cc1, tid);
    phase<3,7,K,K,   3,7,K,K>  (8*K-4, soff, g, chart, X0,X1, Y0,Y1, cc0,cc1, tid);
    phase<3,7,K,K,   3,7,K,K+1>(8*K-2, soff, g, chart, Y0,Y1, X0,X1, cc0,cc1, tid);
}

__global__ __launch_bounds__(NT)
void cky_fused_kernel(const float* __restrict__ scores,
                      const int* __restrict__ cpos,
                      float* __restrict__ ws)
{
    __shared__ float2 chart[NCPAD];

    const int b   = blockIdx.x;
    const int tid = threadIdx.x;
    const float* __restrict__ g = scores + (size_t)b * TOTAL;

    const int4* __restrict__ cp4 = (const int4*)(cpos + b * NCONSTR);
    const int4 cc0 = cp4[0];
    const int4 cc1 = cp4[1];

    float a0[16], a1[16], b0[16], b1[16];

    // initial prefetch: level-1 scores under unfused T=4 mapping
    {
        const int pos = tid>>2, sub = tid&3;
        if (sub==0 && pos<127) a0[0] = g[pos];
    }
    // zero chart incl. pad
    #pragma unroll
    for (int k=0;k<17;k++){
        const int i = tid + k*NT;
        if (i < NCPAD) chart[i] = make_float2(0.f,0.f);
    }
    level_barrier();

    int soff = 0;

    // ---- levels 1..7 unfused (T=4, S=G=16) ----
    phase<2,16,1,0, 2,16,1,0>(1, soff, g, chart, a0,a1, b0,b1, cc0,cc1, tid);
    phase<2,16,1,0, 2,16,1,0>(2, soff, g, chart, b0,b1, a0,a1, cc0,cc1, tid);
    phase<2,16,1,0, 2,16,1,0>(3, soff, g, chart, a0,a1, b0,b1, cc0,cc1, tid);
    phase<2,16,1,0, 2,16,2,0>(4, soff, g, chart, b0,b1, a0,a1, cc0,cc1, tid);
    phase<2,16,2,0, 2,16,2,0>(5, soff, g, chart, a0,a1, b0,b1, cc0,cc1, tid);
    phase<2,16,2,0, 2,16,2,0>(6, soff, g, chart, b0,b1, a0,a1, cc0,cc1, tid);
    phase<2,16,2,0, 2,15,2,3>(7, soff, g, chart, a0,a1, b0,b1, cc0,cc1, tid);
    // ---- levels 8..59 fused T=4 (stride 15) ----
    segf4<3> (soff, g, chart, b0,b1, a0,a1, cc0,cc1, tid);
    segf4<4> (soff, g, chart, b0,b1, a0,a1, cc0,cc1, tid);
    segf4<5> (soff, g, chart, b0,b1, a0,a1, cc0,cc1, tid);
    segf4<6> (soff, g, chart, b0,b1, a0,a1, cc0,cc1, tid);
    segf4<7> (soff, g, chart, b0,b1, a0,a1, cc0,cc1, tid);
    segf4<8> (soff, g, chart, b0,b1, a0,a1, cc0,cc1, tid);
    segf4<9> (soff, g, chart, b0,b1, a0,a1, cc0,cc1, tid);
    segf4<10>(soff, g, chart, b0,b1, a0,a1, cc0,cc1, tid);
    segf4<11>(soff, g, chart, b0,b1, a0,a1, cc0,cc1, tid);
    segf4<12>(soff, g, chart, b0,b1, a0,a1, cc0,cc1, tid);
    segf4<13>(soff, g, chart, b0,b1, a0,a1, cc0,cc1, tid);
    segf4<14>(soff, g, chart, b0,b1, a0,a1, cc0,cc1, tid);
    segf4<15>(soff, g, chart, b0,b1, a0,a1, cc0,cc1, tid);
    // ---- levels 60..63 fused T=4 ----
    phase<2,15,16,16, 2,15,16,16>(60, soff, g, chart, b0,b1, a0,a1, cc0,cc1, tid);
    phase<2,15,16,16, 3,8,8,0>   (62, soff, g, chart, a0,a1, b0,b1, cc0,cc1, tid);
    // ---- levels 64..71 unfused (T=8, S=G=8) ----
    phase<3,8,8,0, 3,8,9,0> (64, soff, g, chart, b0,b1, a0,a1, cc0,cc1, tid);
    phase<3,8,9,0, 3,8,9,0> (65, soff, g, chart, a0,a1, b0,b1, cc0,cc1, tid);
    phase<3,8,9,0, 3,8,9,0> (66, soff, g, chart, b0,b1, a0,a1, cc0,cc1, tid);
    phase<3,8,9,0, 3,8,9,0> (67, soff, g, chart, a0,a1, b0,b1, cc0,cc1, tid);
    phase<3,8,9,0, 3,8,9,0> (68, soff, g, chart, b0,b1, a0,a1, cc0,cc1, tid);
    phase<3,8,9,0, 3,8,9,0> (69, soff, g, chart, a0,a1, b0,b1, cc0,cc1, tid);
    phase<3,8,9,0, 3,8,9,0> (70, soff, g, chart, b0,b1, a0,a1, cc0,cc1, tid);
    phase<3,8,9,0, 3,7,9,10>(71, soff, g, chart, a0,a1, b0,b1, cc0,cc1, tid);
    // ---- levels 72..102 fused T=8 (stride 7) ----
    segf8<10>(soff, g, chart, b0,b1, a0,a1, cc0,cc1, tid);
    segf8<11>(soff, g, chart, b0,b1, a0,a1, cc0,cc1, tid);
    segf8<12>(soff, g, chart, b0,b1, a0,a1, cc0,cc1, tid);
    segf8<13>(soff, g, chart, b0,b1, a0,a1, cc0,cc1, tid);
    // ---- levels 104..110 fused T=8 ----
    phase<3,7,13,14, 3,7,14,14>(104, soff, g, chart, b0,b1, a0,a1, cc0,cc1, tid);
    phase<3,7,14,14, 3,7,14,14>(106, soff, g, chart, a0,a1, b0,b1, cc0,cc1, tid);
    phase<3,7,14,14, 3,7,14,14>(108, soff, g, chart, b0,b1, a0,a1, cc0,cc1, tid);
    phase<3,7,14,14, 4,3,7,8>  (110, soff, g, chart, a0,a1, b0,b1, cc0,cc1, tid);
    // ---- levels 112..127 fused T=16 (stride 3) ----
    phase<4,3,7,8, 4,3,8,8>(112, soff, g, chart, b0,b1, a0,a1, cc0,cc1, tid);
    phase<4,3,8,8, 4,3,8,8>(114, soff, g, chart, a0,a1, b0,b1, cc0,cc1, tid);
    phase<4,3,8,8, 4,3,8,8>(116, soff, g, chart, b0,b1, a0,a1, cc0,cc1, tid);
    phase<4,3,8,8, 4,3,8,8>(118, soff, g, chart, a0,a1, b0,b1, cc0,cc1, tid);
    phase<4,3,8,8, 4,3,8,8>(120, soff, g, chart, b0,b1, a0,a1, cc0,cc1, tid);
    phase<4,3,8,8, 4,3,8,8>(122, soff, g, chart, a0,a1, b0,b1, cc0,cc1, tid);
    phase<4,3,8,8, 4,3,8,8>(124, soff, g, chart, b0,b1, a0,a1, cc0,cc1, tid);
    phase<4,3,8,8, 2,16,0,0>(126, soff, g, chart, a0,a1, b0,b1, cc0,cc1, tid);

    // ---- per-batch hinge contribution ----
    if (tid == 0) {
        const float2 f = chart[OFFi(127)];          // root = cell 8255
        const float pred   = f.x;
        const float constr = f.y - BONUS * NCONSTR;
        const float diff   = pred - constr;
        const float mask   = (fabsf(diff) >= 0.001f) ? 1.f : 0.f;
        const float hinge  = fmaxf(1.0f + diff, 0.f) * mask;
        atomicAdd(ws + 0, hinge);
        atomicAdd(ws + 1, mask);
    }
}

__global__ void final_kernel(const float* __restrict__ ws, float* __restrict__ out) {
    const float h = ws[0];
    const float m = ws[1];
    out[0] = (m > 0.1f) ? (h / fmaxf(m, 1.f)) : h;
}

extern "C" void kernel_launch(void* const* d_in, const int* in_sizes, int n_in,
                              void* d_out, int out_size, void* d_ws, size_t ws_size,
                              hipStream_t stream) {
    const float* scores = (const float*)d_in[0];
    const int*   cpos   = (const int*)d_in[1];
    float* out = (float*)d_out;
    float* ws  = (float*)d_ws;

    hipMemsetAsync(ws, 0, 2 * sizeof(float), stream);
    cky_fused_kernel<<<dim3(256), dim3(NT), 0, stream>>>(scores, cpos, ws);
    final_kernel<<<dim3(1), dim3(1), 0, stream>>>(ws, out);
}

// Round 10
// 148.092 us; speedup vs baseline: 1.1462x; 1.1462x over previous
//
#include <hip/hip_runtime.h>
#include <hip/hip_bf16.h>
#include <math.h>

#define LEN 128
#define NCELLS 8256
#define TOTAL 349504
#define NCONSTR 8
#define BONUS 1000.0f
#define NT 512

__device__ __host__ constexpr int OFFi(int n){ return (n*(257-n))>>1; }
constexpr int SOFFc(int l){ int s=0; for(int k=1;k<l;k++) s += (LEN-k)*k; return s; }

// Barrier WITHOUT vmcnt drain (score prefetch stays in flight; T4 discipline).
__device__ __forceinline__ void level_barrier(){
    __builtin_amdgcn_sched_barrier(0);
    asm volatile("s_waitcnt lgkmcnt(0)\n\ts_barrier" ::: "memory");
    __builtin_amdgcn_sched_barrier(0);
}

__device__ __forceinline__ float dpp_xor1_max(float v){
    int r = __builtin_amdgcn_update_dpp(0, __float_as_int(v), 0xB1, 0xF, 0xF, true);
    return fmaxf(v, __int_as_float(r));
}
__device__ __forceinline__ float dpp_xor2_max(float v){
    int r = __builtin_amdgcn_update_dpp(0, __float_as_int(v), 0x4E, 0xF, 0xF, true);
    return fmaxf(v, __int_as_float(r));
}
template<int LG>
__device__ __forceinline__ void redmax2(float& a, float& b){
    #pragma unroll
    for (int mm=(1<<LG)>>1; mm>=4; mm>>=1){
        a=fmaxf(a,__shfl_xor(a,mm));
        b=fmaxf(b,__shfl_xor(b,mm));
    }
    if constexpr (LG>=2){ a=dpp_xor2_max(a); b=dpp_xor2_max(b); }
    if constexpr (LG>=1){ a=dpp_xor1_max(a); b=dpp_xor1_max(b); }
}

__device__ __forceinline__ bool chit(int q, const int4 c0, const int4 c1){
    return (q==c0.x)|(q==c0.y)|(q==c0.z)|(q==c0.w)|
           (q==c1.x)|(q==c1.y)|(q==c1.z)|(q==c1.w);
}

// One level, left column carried in registers (lv), right diagonal from LDS.
template<int LVL, int LG, int LG2>
__device__ __forceinline__ void lstep(const float* __restrict__ g,
    float2* __restrict__ chart, float2 (&lv)[16],
    float (&xc)[16], float (&xn)[16],
    const int4 cc0, const int4 cc1, const int tid)
{
    constexpr int N = LVL, L = LEN - LVL;
    constexpr int T = 1<<LG;
    constexpr int JM = (N + T - 1)/T;
    const int pos = tid >> LG;
    const int sub = tid & (T-1);

    // ---- prefetch next level's scores (in flight across the barrier) ----
    if constexpr (LVL < 127){
        constexpr int T2 = 1<<LG2;
        constexpr int N2 = LVL+1, L2 = LEN-LVL-1;
        constexpr int JM2 = (N2 + T2 - 1)/T2;
        constexpr int SO = SOFFc(LVL+1);
        const int pos2 = tid >> LG2;
        const int sub2 = tid & (T2-1);
        if (pos2 < L2){
            const float* __restrict__ gp = g + SO + pos2*N2 + sub2;
            #pragma unroll
            for (int j=0;j<JM2;j++)
                if (sub2 + j*T2 < N2) xn[j] = gp[j*T2];
        }
    }

    // ---- right-child burst (LDS; rows 0..N-1, all finalized) ----
    float2 rv[JM];
    if (pos < L){
        #pragma unroll
        for (int j=0;j<JM;j++){
            const int n = sub + j*T;
            const int ri = (n < N) ? (OFFi(N-1-n) + pos + n + 1) : 0;
            rv[j] = chart[ri];
        }
    }

    // ---- compute ----
    float bp = -INFINITY, bc = -INFINITY;
    if (pos < L){
        #pragma unroll
        for (int j=0;j<JM;j++){
            const int n = sub + j*T;
            const float x = (n < N) ? xc[j] : -INFINITY;
            bp = fmaxf(bp, lv[j].x + rv[j].x + x);
            bc = fmaxf(bc, lv[j].y + rv[j].y + x);
        }
    }
    redmax2<LG>(bp, bc);

    const int q = OFFi(N) + pos;
    const float bon = chit(q, cc0, cc1) ? BONUS : 0.f;
    const float2 cv = make_float2(bp, bc + bon);
    if (pos < L && sub == 0) chart[q] = cv;

    // ---- append own output to the register left column (compile-time slot) ----
    {
        constexpr int asub  = N & (T-1);
        constexpr int aslot = N >> LG;
        static_assert(aslot < 16, "slot overflow");
        if (sub == asub){ lv[aslot] = cv; }
    }

    level_barrier();
}

// T 4 -> 8 transition: re-read left column under the T=8 mapping (rows 0..63,
// all finalized and barrier-visible after level 63).
__device__ __forceinline__ void trans64(const float2* __restrict__ chart,
                                        float2 (&lv)[16], const int tid)
{
    const int pos = tid >> 3;       // 0..63
    const int sub = tid & 7;
    #pragma unroll
    for (int j=0;j<8;j++){
        const int n = sub + 8*j;    // 0..63
        lv[j] = chart[OFFi(n) + pos];
    }
}

template<int L>
__device__ __forceinline__ void runlv(const float* __restrict__ g,
    float2* __restrict__ chart, float2 (&lv)[16],
    float (&xc)[16], float (&xn)[16],
    const int4 cc0, const int4 cc1, const int tid)
{
    if constexpr (L <= 127){
        constexpr int LG  = (L < 64) ? 2 : 3;
        constexpr int LG2 = (L+1 < 64) ? 2 : 3;
        lstep<L, LG, LG2>(g, chart, lv, xc, xn, cc0, cc1, tid);
        if constexpr (L == 63) trans64(chart, lv, tid);
        runlv<L+1>(g, chart, lv, xn, xc, cc0, cc1, tid);
    }
}

__global__ __launch_bounds__(NT)
void cky_fused_kernel(const float* __restrict__ scores,
                      const int* __restrict__ cpos,
                      float* __restrict__ ws)
{
    __shared__ float2 chart[NCELLS];   // .x = pred, .y = constr

    const int b   = blockIdx.x;
    const int tid = threadIdx.x;
    const float* __restrict__ g = scores + (size_t)b * TOTAL;

    const int4* __restrict__ cp4 = (const int4*)(cpos + b * NCONSTR);
    const int4 cc0 = cp4[0];
    const int4 cc1 = cp4[1];

    float  xA[16], xB[16];
    float2 lv[16];
    #pragma unroll
    for (int j=0;j<16;j++) lv[j] = make_float2(0.f, 0.f);

    // level-1 score prefetch (T=4 mapping)
    {
        const int pos = tid>>2, sub = tid&3;
        if (sub==0 && pos<127) xA[0] = g[pos];
    }

    // zero ONLY row 0 (cells 0..127): every other cell is written before read;
    // masked/tail reads clamp to row 0.
    if (tid < 128) chart[tid] = make_float2(0.f, 0.f);
    level_barrier();

    runlv<1>(g, chart, lv, xA, xB, cc0, cc1, tid);

    // ---- per-batch hinge contribution ----
    if (tid == 0){
        const float2 f = chart[OFFi(127)];          // root = cell 8255
        const float pred   = f.x;
        const float constr = f.y - BONUS * NCONSTR;
        const float diff   = pred - constr;
        const float mask   = (fabsf(diff) >= 0.001f) ? 1.f : 0.f;
        const float hinge  = fmaxf(1.0f + diff, 0.f) * mask;
        atomicAdd(ws + 0, hinge);
        atomicAdd(ws + 1, mask);
    }
}

__global__ void final_kernel(const float* __restrict__ ws, float* __restrict__ out){
    const float h = ws[0];
    const float m = ws[1];
    out[0] = (m > 0.1f) ? (h / fmaxf(m, 1.f)) : h;
}

extern "C" void kernel_launch(void* const* d_in, const int* in_sizes, int n_in,
                              void* d_out, int out_size, void* d_ws, size_t ws_size,
                              hipStream_t stream) {
    const float* scores = (const float*)d_in[0];
    const int*   cpos   = (const int*)d_in[1];
    float* out = (float*)d_out;
    float* ws  = (float*)d_ws;

    hipMemsetAsync(ws, 0, 2 * sizeof(float), stream);
    cky_fused_kernel<<<dim3(256), dim3(NT), 0, stream>>>(scores, cpos, ws);
    final_kernel<<<dim3(1), dim3(1), 0, stream>>>(ws, out);
}

// Round 11
// 143.805 us; speedup vs baseline: 1.1804x; 1.0298x over previous
//
#include <hip/hip_runtime.h>
#include <hip/hip_bf16.h>
#include <math.h>

#define LEN 128
#define NCELLS 8256          // LEN*(LEN+1)/2
#define TOTAL 349504         // sum_{l=1}^{127} (128-l)*l
#define NCONSTR 8
#define BONUS 1000.0f
#define NT 512

// Barrier WITHOUT vmcnt drain: only LDS writes must be ordered; register
// score-prefetch loads stay in flight across the barrier (T4 discipline).
__device__ __forceinline__ void level_barrier() {
    __builtin_amdgcn_sched_barrier(0);
    asm volatile("s_waitcnt lgkmcnt(0)\n\ts_barrier" ::: "memory");
    __builtin_amdgcn_sched_barrier(0);
}

// DPP quad_perm cross-lane max (VALU pipe, no LDS traffic).
__device__ __forceinline__ float dpp_xor1_max(float v) {
    int r = __builtin_amdgcn_update_dpp(0, __float_as_int(v), 0xB1, 0xF, 0xF, true);
    return fmaxf(v, __int_as_float(r));
}
__device__ __forceinline__ float dpp_xor2_max(float v) {
    int r = __builtin_amdgcn_update_dpp(0, __float_as_int(v), 0x4E, 0xF, 0xF, true);
    return fmaxf(v, __int_as_float(r));
}

template<int LG>
__device__ __forceinline__ void redmax2(float& a, float& b) {
    #pragma unroll
    for (int mm = (1 << LG) >> 1; mm >= 4; mm >>= 1) {
        a = fmaxf(a, __shfl_xor(a, mm));
        b = fmaxf(b, __shfl_xor(b, mm));
    }
    if constexpr (LG >= 2) { a = dpp_xor2_max(a); b = dpp_xor2_max(b); }
    if constexpr (LG >= 1) { a = dpp_xor1_max(a); b = dpp_xor1_max(b); }
}

// One CKY level (r4-verified body). Phase 1: issue all 2*JM independent
// ds_read_b64 into register arrays; phase 2: consume. DEPTH-2 PREFETCH:
// loads scores for level+2 into rnxt (crosses TWO barriers before use).
template<int LG, int LG2, int JM, int JM2>
__device__ __forceinline__ void lstep(const int level, int& soff,
        const float* __restrict__ g, float2* __restrict__ chart,
        float (&rcur)[16], float (&rnxt)[16], const int tid)
{
    const int N = level;
    const int L = LEN - level;
    constexpr int T = 1 << LG;
    const int pos = tid >> LG;
    const int sub = tid & (T - 1);
    const int soff_n = soff + L * N;

    // ---- issue score loads for level+2 (consumed after two barriers) ----
    if constexpr (LG2 >= 0) {
        constexpr int T2 = 1 << LG2;
        const int N2 = level + 2;
        const int L2 = L - 2;
        const int soff_nn = soff_n + (L - 1) * (N + 1);
        const int pos2 = tid >> LG2;
        const int sub2 = tid & (T2 - 1);
        if (pos2 < L2) {
            const float* __restrict__ gp = g + soff_nn + pos2 * N2 + sub2;
            #pragma unroll
            for (int j = 0; j < JM2; j++) {
                if (sub2 + j * T2 < N2) rnxt[j] = gp[j * T2];
            }
        }
    }

    // ---- compute this level ----
    float bp = -INFINITY, bc = -INFINITY;
    if (pos < L) {
        const int jml = (N - sub + T - 1) >> LG;   // per-lane valid trip count
        float2 lv[JM], rv[JM];
        float  xs[JM];
        #pragma unroll
        for (int j = 0; j < JM; j++) {
            const int n = sub + j * T;
            const int m = level - 1 - n;
            const bool v = (j < jml);
            const int l_idx = ((n * (257 - n)) >> 1) + pos;
            int r_idx = ((m * (257 - m)) >> 1) + pos + n + 1;
            r_idx = v ? r_idx : 0;
            lv[j] = chart[l_idx];
            rv[j] = chart[r_idx];
            xs[j] = v ? rcur[j] : -INFINITY;
        }
        #pragma unroll
        for (int j = 0; j < JM; j++) {
            bp = fmaxf(bp, lv[j].x + rv[j].x + xs[j]);
            bc = fmaxf(bc, lv[j].y + rv[j].y + xs[j]);
        }
    }
    redmax2<LG>(bp, bc);
    if (pos < L && sub == 0) {
        const int q = ((level * (257 - level)) >> 1) + pos;
        float2 c = chart[q];
        c.x += bp;
        c.y += bc;
        chart[q] = c;
    }
    level_barrier();
    soff = soff_n;
}

// 4 levels at TPP=4, JM=K exactly (levels 4K-3..4K). Triple-buffer rotation:
// consume X,Y,Z,X; load targets Z,X,Y,Z (level+2). Next seg starts with Y.
template<int K>
__device__ __forceinline__ void seg4(int& soff, const float* __restrict__ g,
        float2* __restrict__ chart, float (&X)[16], float (&Y)[16], float (&Z)[16],
        const int tid)
{
    lstep<2,2,K,K>  (4*K-3, soff, g, chart, X, Z, tid);
    lstep<2,2,K,K>  (4*K-2, soff, g, chart, Y, X, tid);
    lstep<2,2,K,K+1>(4*K-1, soff, g, chart, Z, Y, tid);
    lstep<2,2,K,K+1>(4*K,   soff, g, chart, X, Z, tid);
}

__global__ __launch_bounds__(NT)
void cky_fused_kernel(const float* __restrict__ scores,
                      const int* __restrict__ cpos,
                      float* __restrict__ ws)
{
    __shared__ float2 chart[NCELLS];   // .x = pred chart, .y = constr chart

    const int b   = blockIdx.x;
    const int tid = threadIdx.x;
    const float* __restrict__ g = scores + (size_t)b * TOTAL;

    float rA[16], rB[16], rC[16];

    // ---- prefetch level 1 (A) and level 2 (B) scores (TPP=4 mapping) ----
    {
        const int pos = tid >> 2;
        const int sub = tid & 3;
        if (pos < 127 && sub == 0) rA[0] = g[pos];
        if (pos < 126 && sub < 2)  rB[0] = g[127 + pos * 2 + sub];
    }
    int cp = 0;
    if (tid < NCONSTR) cp = cpos[b * NCONSTR + tid];

    // ---- init both charts ----
    for (int i = tid; i < NCELLS; i += NT) chart[i] = make_float2(0.f, 0.f);
    level_barrier();
    if (tid < NCONSTR) chart[cp].y = BONUS;   // set (not add); duplicates benign
    level_barrier();

    int soff = 0;

    // ---- TPP=4: levels 1..60 (triple-buffer, seg rotation period 3) ----
    seg4<1>(soff, g, chart, rA, rB, rC, tid);
    seg4<2>(soff, g, chart, rB, rC, rA, tid);
    seg4<3>(soff, g, chart, rC, rA, rB, tid);
    seg4<4>(soff, g, chart, rA, rB, rC, tid);
    seg4<5>(soff, g, chart, rB, rC, rA, tid);
    seg4<6>(soff, g, chart, rC, rA, rB, tid);
    seg4<7>(soff, g, chart, rA, rB, rC, tid);
    seg4<8>(soff, g, chart, rB, rC, rA, tid);
    seg4<9>(soff, g, chart, rC, rA, rB, tid);
    seg4<10>(soff, g, chart, rA, rB, rC, tid);
    seg4<11>(soff, g, chart, rB, rC, rA, tid);
    seg4<12>(soff, g, chart, rC, rA, rB, tid);
    seg4<13>(soff, g, chart, rA, rB, rC, tid);
    seg4<14>(soff, g, chart, rB, rC, rA, tid);
    seg4<15>(soff, g, chart, rC, rA, rB, tid);
    // ---- TPP=4 tail: levels 61..63 ----
    lstep<2,2,16,16>(61, soff, g, chart, rA, rC, tid);
    lstep<2,3,16,8> (62, soff, g, chart, rB, rA, tid);   // loads level 64 (T=8)
    lstep<2,3,16,9> (63, soff, g, chart, rC, rB, tid);   // loads level 65
    // ---- TPP=8: levels 64..95 ----
    lstep<3,3,8,9>  (64, soff, g, chart, rA, rC, tid);
    lstep<3,3,9,9>  (65, soff, g, chart, rB, rA, tid);
    lstep<3,3,9,9>  (66, soff, g, chart, rC, rB, tid);
    lstep<3,3,9,9>  (67, soff, g, chart, rA, rC, tid);
    lstep<3,3,9,9>  (68, soff, g, chart, rB, rA, tid);
    lstep<3,3,9,9>  (69, soff, g, chart, rC, rB, tid);
    lstep<3,3,9,9>  (70, soff, g, chart, rA, rC, tid);
    lstep<3,3,9,10> (71, soff, g, chart, rB, rA, tid);
    lstep<3,3,9,10> (72, soff, g, chart, rC, rB, tid);
    lstep<3,3,10,10>(73, soff, g, chart, rA, rC, tid);
    lstep<3,3,10,10>(74, soff, g, chart, rB, rA, tid);
    lstep<3,3,10,10>(75, soff, g, chart, rC, rB, tid);
    lstep<3,3,10,10>(76, soff, g, chart, rA, rC, tid);
    lstep<3,3,10,10>(77, soff, g, chart, rB, rA, tid);
    lstep<3,3,10,10>(78, soff, g, chart, rC, rB, tid);
    lstep<3,3,10,11>(79, soff, g, chart, rA, rC, tid);
    lstep<3,3,10,11>(80, soff, g, chart, rB, rA, tid);
    lstep<3,3,11,11>(81, soff, g, chart, rC, rB, tid);
    lstep<3,3,11,11>(82, soff, g, chart, rA, rC, tid);
    lstep<3,3,11,11>(83, soff, g, chart, rB, rA, tid);
    lstep<3,3,11,11>(84, soff, g, chart, rC, rB, tid);
    lstep<3,3,11,11>(85, soff, g, chart, rA, rC, tid);
    lstep<3,3,11,11>(86, soff, g, chart, rB, rA, tid);
    lstep<3,3,11,12>(87, soff, g, chart, rC, rB, tid);
    lstep<3,3,11,12>(88, soff, g, chart, rA, rC, tid);
    lstep<3,3,12,12>(89, soff, g, chart, rB, rA, tid);
    lstep<3,3,12,12>(90, soff, g, chart, rC, rB, tid);
    lstep<3,3,12,12>(91, soff, g, chart, rA, rC, tid);
    lstep<3,3,12,12>(92, soff, g, chart, rB, rA, tid);
    lstep<3,3,12,12>(93, soff, g, chart, rC, rB, tid);
    lstep<3,4,12,6> (94, soff, g, chart, rA, rC, tid);   // loads level 96 (T=16)
    lstep<3,4,12,7> (95, soff, g, chart, rB, rA, tid);   // loads level 97
    // ---- TPP=16: levels 96..111 ----
    lstep<4,4,6,7>  (96, soff, g, chart, rC, rB, tid);
    lstep<4,4,7,7>  (97, soff, g, chart, rA, rC, tid);
    lstep<4,4,7,7>  (98, soff, g, chart, rB, rA, tid);
    lstep<4,4,7,7>  (99, soff, g, chart, rC, rB, tid);
    lstep<4,4,7,7> (100, soff, g, chart, rA, rC, tid);
    lstep<4,4,7,7> (101, soff, g, chart, rB, rA, tid);
    lstep<4,4,7,7> (102, soff, g, chart, rC, rB, tid);
    lstep<4,4,7,7> (103, soff, g, chart, rA, rC, tid);
    lstep<4,4,7,7> (104, soff, g, chart, rB, rA, tid);
    lstep<4,4,7,7> (105, soff, g, chart, rC, rB, tid);
    lstep<4,4,7,7> (106, soff, g, chart, rA, rC, tid);
    lstep<4,4,7,7> (107, soff, g, chart, rB, rA, tid);
    lstep<4,4,7,7> (108, soff, g, chart, rC, rB, tid);
    lstep<4,4,7,7> (109, soff, g, chart, rA, rC, tid);
    lstep<4,5,7,4> (110, soff, g, chart, rB, rA, tid);   // loads level 112 (T=32)
    lstep<4,5,7,4> (111, soff, g, chart, rC, rB, tid);   // loads level 113
    // ---- TPP=32: levels 112..119 ----
    lstep<5,5,4,4>(112, soff, g, chart, rA, rC, tid);
    lstep<5,5,4,4>(113, soff, g, chart, rB, rA, tid);
    lstep<5,5,4,4>(114, soff, g, chart, rC, rB, tid);
    lstep<5,5,4,4>(115, soff, g, chart, rA, rC, tid);
    lstep<5,5,4,4>(116, soff, g, chart, rB, rA, tid);
    lstep<5,5,4,4>(117, soff, g, chart, rC, rB, tid);
    lstep<5,6,4,2>(118, soff, g, chart, rA, rC, tid);    // loads level 120 (T=64)
    lstep<5,6,4,2>(119, soff, g, chart, rB, rA, tid);    // loads level 121
    // ---- TPP=64: levels 120..127 ----
    lstep<6,6,2,2>(120, soff, g, chart, rC, rB, tid);
    lstep<6,6,2,2>(121, soff, g, chart, rA, rC, tid);
    lstep<6,6,2,2>(122, soff, g, chart, rB, rA, tid);
    lstep<6,6,2,2>(123, soff, g, chart, rC, rB, tid);
    lstep<6,6,2,2>(124, soff, g, chart, rA, rC, tid);
    lstep<6,6,2,2>(125, soff, g, chart, rB, rA, tid);
    lstep<6,-1,2,0>(126, soff, g, chart, rC, rB, tid);
    lstep<6,-1,2,0>(127, soff, g, chart, rA, rB, tid);   // root

    // ---- per-batch hinge contribution ----
    if (tid == 0) {
        const float2 f = chart[NCELLS - 1];
        const float pred   = f.x;
        const float constr = f.y - BONUS * NCONSTR;
        const float diff   = pred - constr;
        const float mask   = (fabsf(diff) >= 0.001f) ? 1.f : 0.f;
        const float hinge  = fmaxf(1.0f + diff, 0.f) * mask;
        atomicAdd(ws + 0, hinge);
        atomicAdd(ws + 1, mask);
    }
}

__global__ void final_kernel(const float* __restrict__ ws, float* __restrict__ out) {
    const float h = ws[0];
    const float m = ws[1];
    out[0] = (m > 0.1f) ? (h / fmaxf(m, 1.f)) : h;
}

extern "C" void kernel_launch(void* const* d_in, const int* in_sizes, int n_in,
                              void* d_out, int out_size, void* d_ws, size_t ws_size,
                              hipStream_t stream) {
    const float* scores = (const float*)d_in[0];
    const int*   cpos   = (const int*)d_in[1];
    float* out = (float*)d_out;
    float* ws  = (float*)d_ws;

    hipMemsetAsync(ws, 0, 2 * sizeof(float), stream);
    cky_fused_kernel<<<dim3(256), dim3(NT), 0, stream>>>(scores, cpos, ws);
    final_kernel<<<dim3(1), dim3(1), 0, stream>>>(ws, out);
}